// Round 2
// baseline (223.826 us; speedup 1.0000x reference)
//
#include <hip/hip_runtime.h>
#include <math.h>

#define MM 4096
#define DD 2048

typedef float floatx4 __attribute__((ext_vector_type(4)));

// ws layout (floats):
// [0..M)    qt
// [M..2M)   k (scaled by 1/sqrt(M))
// [2M..3M)  v
// [3M+0] it, [3M+1] ft, [3M+2] ot, [3M+3] denom
// [4M..5M)  num (per-row C@qt numerator)

// ---------------- K1: qt/k/v GEMVs (direct loads, 1 row/wave) + gate scalars ----------------
// W rows have zero reuse -> no LDS staging (it was pure latency overhead).
__global__ __launch_bounds__(256) void k1_gemv_gates(
    const float* __restrict__ x,
    const float* __restrict__ Wq, const float* __restrict__ bq,
    const float* __restrict__ Wk, const float* __restrict__ bk,
    const float* __restrict__ Wv, const float* __restrict__ bV,
    const float* __restrict__ Wi, const float* __restrict__ bi,
    const float* __restrict__ Wf, const float* __restrict__ bf,
    const float* __restrict__ Wo, const float* __restrict__ bo,
    float* __restrict__ ws)
{
    const int lane = threadIdx.x & 63;
    const int wid  = threadIdx.x >> 6;

    if (blockIdx.x >= 3072) {
        // ----- gate blocks: double-precision dot over D -----
        __shared__ double gred[4];
        const int g = blockIdx.x - 3072;           // 0=i, 1=f, 2=o
        const float* G = (g == 0) ? Wi : ((g == 1) ? Wf : Wo);
        const float4* g4 = (const float4*)G;
        const float4* xv = (const float4*)x;
        double acc = 0.0;
        for (int t = threadIdx.x; t < DD / 4; t += 256) {
            float4 gg = g4[t];
            float4 xx = xv[t];
            acc += (double)gg.x * xx.x + (double)gg.y * xx.y
                 + (double)gg.z * xx.z + (double)gg.w * xx.w;
        }
        for (int off = 32; off; off >>= 1) acc += __shfl_down(acc, off, 64);
        if (lane == 0) gred[wid] = acc;
        __syncthreads();
        if (threadIdx.x == 0) {
            double s = gred[0] + gred[1] + gred[2] + gred[3];
            if (g == 0)      ws[3 * MM + 0] = (float)exp(s + (double)bi[0]);
            else if (g == 1) ws[3 * MM + 1] = (float)exp(s + (double)bf[0]);
            else             ws[3 * MM + 2] = (float)(1.0 / (1.0 + exp(-(s + (double)bo[0]))));
        }
        return;
    }

    // ----- row blocks: 4 waves, one (matrix,row) dot per wave -----
    __shared__ float xs[DD];                 // 8 KB only -> high occupancy

    {   // stage x once
        const float4* xv  = (const float4*)x;
        float4*       xsv = (float4*)xs;
        xsv[threadIdx.x]       = xv[threadIdx.x];
        xsv[256 + threadIdx.x] = xv[256 + threadIdx.x];
    }
    __syncthreads();

    const int m   = blockIdx.x >> 10;                  // 0=q, 1=k, 2=v
    const int row = ((blockIdx.x & 1023) << 2) + wid;

    const float* W = (m == 0) ? Wq : ((m == 1) ? Wk : Wv);
    const float4* w4  = (const float4*)(W + (size_t)row * DD);
    const float4* xs4 = (const float4*)xs;

    float acc = 0.f;
    #pragma unroll
    for (int t = 0; t < DD / 4 / 64; ++t) {            // 8 iters, fully unrolled
        float4 ww = w4 [t * 64 + lane];
        float4 xx = xs4[t * 64 + lane];
        acc += ww.x * xx.x + ww.y * xx.y + ww.z * xx.z + ww.w * xx.w;
    }

    for (int off = 32; off; off >>= 1) acc += __shfl_down(acc, off, 64);

    if (lane == 0) {
        if (m == 0)      ws[row]          = acc + bq[row];
        else if (m == 1) ws[MM + row]     = (acc + bk[row]) * (1.0f / 64.0f); // 1/sqrt(4096)
        else             ws[2 * MM + row] = acc + bV[row];
    }
}

// ---------------- K2: 4 rows per block (1 per wave), q/k staged in LDS once ----------------
// Removes the 128 MB of redundant q/k re-reads through the global path
// (4096 blocks x 32 KB -> 1024 blocks x 32 KB = 32 MB). No per-row barriers.
__global__ __launch_bounds__(256) void k2_rowC(
    const float* __restrict__ cp, const float* __restrict__ n_prev,
    float* __restrict__ ws, float* __restrict__ C_out, float* __restrict__ n_out)
{
    const int lane = threadIdx.x & 63;
    const int wid  = threadIdx.x >> 6;

    if (blockIdx.x == 1024) {
        // ----- n & denom block -----
        __shared__ float pred[4];
        const float it = ws[3 * MM + 0];
        const float ft = ws[3 * MM + 1];
        const float4* np4 = (const float4*)n_prev;
        const float4* kv4 = (const float4*)(ws + MM);
        const float4* qv4 = (const float4*)ws;
        float4* n4 = (float4*)n_out;
        float acc = 0.f;
        #pragma unroll
        for (int u = 0; u < 4; ++u) {
            int t = threadIdx.x + 256 * u;
            float4 np = np4[t], kk = kv4[t], qq = qv4[t];
            float4 nn;
            nn.x = fmaf(ft, np.x, it * kk.x);
            nn.y = fmaf(ft, np.y, it * kk.y);
            nn.z = fmaf(ft, np.z, it * kk.z);
            nn.w = fmaf(ft, np.w, it * kk.w);
            n4[t] = nn;
            acc += nn.x * qq.x + nn.y * qq.y + nn.z * qq.z + nn.w * qq.w;
        }
        for (int off = 32; off; off >>= 1) acc += __shfl_down(acc, off, 64);
        if (lane == 0) pred[wid] = acc;
        __syncthreads();
        if (threadIdx.x == 0) {
            float s = pred[0] + pred[1] + pred[2] + pred[3];
            ws[3 * MM + 3] = fmaxf(fabsf(s), 1.0f);
        }
        return;
    }

    __shared__ float4 kq[2][MM / 4];          // [0]=k, [1]=q : 32 KB
    const float it = ws[3 * MM + 0];
    const float ft = ws[3 * MM + 1];

    {   // stage k and q once per block
        const float4* kv4 = (const float4*)(ws + MM);
        const float4* qv4 = (const float4*)ws;
        #pragma unroll
        for (int u = 0; u < 4; ++u) kq[0][threadIdx.x + 256 * u] = kv4[threadIdx.x + 256 * u];
        #pragma unroll
        for (int u = 0; u < 4; ++u) kq[1][threadIdx.x + 256 * u] = qv4[threadIdx.x + 256 * u];
    }
    __syncthreads();

    const int row = (blockIdx.x << 2) + wid;   // one row per wave
    const float ivi = it * ws[2 * MM + row];

    const float4* cprow = (const float4*)(cp + (size_t)row * MM);
    float4*       crow  = (float4*)(C_out + (size_t)row * MM);

    float acc = 0.f;
    #pragma unroll
    for (int u = 0; u < 16; ++u) {
        const int idx = lane + 64 * u;
        float4 c  = cprow[idx];
        float4 kk = kq[0][idx];
        float4 qq = kq[1][idx];
        float4 o;
        o.x = fmaf(ivi, kk.x, ft * c.x);
        o.y = fmaf(ivi, kk.y, ft * c.y);
        o.z = fmaf(ivi, kk.z, ft * c.z);
        o.w = fmaf(ivi, kk.w, ft * c.w);
        floatx4 ov = { o.x, o.y, o.z, o.w };
        __builtin_nontemporal_store(ov, (floatx4*)(crow + idx));
        acc += o.x * qq.x + o.y * qq.y + o.z * qq.z + o.w * qq.w;
    }
    for (int off = 32; off; off >>= 1) acc += __shfl_down(acc, off, 64);
    if (lane == 0) ws[4 * MM + row] = acc;
}

// ---------------- K3: ht = ot * num / denom ----------------
__global__ __launch_bounds__(256) void k3_finalize(
    const float* __restrict__ ws, float* __restrict__ ht_out)
{
    const float ot    = ws[3 * MM + 2];
    const float denom = ws[3 * MM + 3];
    const int i = blockIdx.x * 256 + threadIdx.x;
    ht_out[i] = ot * (ws[4 * MM + i] / denom);
}

extern "C" void kernel_launch(void* const* d_in, const int* in_sizes, int n_in,
                              void* d_out, int out_size, void* d_ws, size_t ws_size,
                              hipStream_t stream)
{
    const float* x      = (const float*)d_in[0];
    const float* cp     = (const float*)d_in[1];
    const float* n_prev = (const float*)d_in[2];
    const float* Wq = (const float*)d_in[3];
    const float* bq = (const float*)d_in[4];
    const float* Wk = (const float*)d_in[5];
    const float* bk = (const float*)d_in[6];
    const float* Wv = (const float*)d_in[7];
    const float* bV = (const float*)d_in[8];
    const float* Wi = (const float*)d_in[9];
    const float* bi = (const float*)d_in[10];
    const float* Wf = (const float*)d_in[11];
    const float* bf = (const float*)d_in[12];
    const float* Wo = (const float*)d_in[13];
    const float* bo = (const float*)d_in[14];

    float* out = (float*)d_out;
    float* ht  = out;                        // (M,1)
    float* C   = out + MM;                   // (M,M)
    float* n   = out + MM + (size_t)MM * MM; // (M,1)
    float* ws  = (float*)d_ws;

    k1_gemv_gates<<<3075, 256, 0, stream>>>(x, Wq, bq, Wk, bk, Wv, bV,
                                            Wi, bi, Wf, bf, Wo, bo, ws);
    k2_rowC      <<<1025, 256, 0, stream>>>(cp, n_prev, ws, C, n);
    k3_finalize  <<<MM / 256, 256, 0, stream>>>(ws, ht);
}

// Round 3
// 222.115 us; speedup vs baseline: 1.0077x; 1.0077x over previous
//
#include <hip/hip_runtime.h>
#include <math.h>

#define MM 4096
#define DD 2048

typedef float floatx4 __attribute__((ext_vector_type(4)));

// ws layout (floats):
// [0..M)    qt
// [M..2M)   k (scaled by 1/sqrt(M))
// [2M..3M)  v
// [3M+0] it, [3M+1] ft, [3M+2] ot, [3M+3] denom
// [4M..5M)  num (per-row C@qt numerator)

// ---------------- K1: qt/k/v GEMVs (direct loads, 1 row/wave) + gate scalars ----------------
__global__ __launch_bounds__(256) void k1_gemv_gates(
    const float* __restrict__ x,
    const float* __restrict__ Wq, const float* __restrict__ bq,
    const float* __restrict__ Wk, const float* __restrict__ bk,
    const float* __restrict__ Wv, const float* __restrict__ bV,
    const float* __restrict__ Wi, const float* __restrict__ bi,
    const float* __restrict__ Wf, const float* __restrict__ bf,
    const float* __restrict__ Wo, const float* __restrict__ bo,
    float* __restrict__ ws)
{
    const int lane = threadIdx.x & 63;
    const int wid  = threadIdx.x >> 6;

    if (blockIdx.x >= 3072) {
        // ----- gate blocks: double-precision dot over D -----
        __shared__ double gred[4];
        const int g = blockIdx.x - 3072;           // 0=i, 1=f, 2=o
        const float* G = (g == 0) ? Wi : ((g == 1) ? Wf : Wo);
        const float4* g4 = (const float4*)G;
        const float4* xv = (const float4*)x;
        double acc = 0.0;
        for (int t = threadIdx.x; t < DD / 4; t += 256) {
            float4 gg = g4[t];
            float4 xx = xv[t];
            acc += (double)gg.x * xx.x + (double)gg.y * xx.y
                 + (double)gg.z * xx.z + (double)gg.w * xx.w;
        }
        for (int off = 32; off; off >>= 1) acc += __shfl_down(acc, off, 64);
        if (lane == 0) gred[wid] = acc;
        __syncthreads();
        if (threadIdx.x == 0) {
            double s = gred[0] + gred[1] + gred[2] + gred[3];
            if (g == 0)      ws[3 * MM + 0] = (float)exp(s + (double)bi[0]);
            else if (g == 1) ws[3 * MM + 1] = (float)exp(s + (double)bf[0]);
            else             ws[3 * MM + 2] = (float)(1.0 / (1.0 + exp(-(s + (double)bo[0]))));
        }
        return;
    }

    // ----- row blocks: 4 waves, one (matrix,row) dot per wave -----
    __shared__ float xs[DD];                 // 8 KB only -> high occupancy

    {   // stage x once
        const float4* xv  = (const float4*)x;
        float4*       xsv = (float4*)xs;
        xsv[threadIdx.x]       = xv[threadIdx.x];
        xsv[256 + threadIdx.x] = xv[256 + threadIdx.x];
    }
    __syncthreads();

    const int m   = blockIdx.x >> 10;                  // 0=q, 1=k, 2=v
    const int row = ((blockIdx.x & 1023) << 2) + wid;

    const float* W = (m == 0) ? Wq : ((m == 1) ? Wk : Wv);
    const float4* w4  = (const float4*)(W + (size_t)row * DD);
    const float4* xs4 = (const float4*)xs;

    float acc = 0.f;
    #pragma unroll
    for (int t = 0; t < DD / 4 / 64; ++t) {            // 8 iters, fully unrolled
        float4 ww = w4 [t * 64 + lane];
        float4 xx = xs4[t * 64 + lane];
        acc += ww.x * xx.x + ww.y * xx.y + ww.z * xx.z + ww.w * xx.w;
    }

    for (int off = 32; off; off >>= 1) acc += __shfl_down(acc, off, 64);

    if (lane == 0) {
        if (m == 0)      ws[row]          = acc + bq[row];
        else if (m == 1) ws[MM + row]     = (acc + bk[row]) * (1.0f / 64.0f); // 1/sqrt(4096)
        else             ws[2 * MM + row] = acc + bV[row];
    }
}

// ---------------- K2: one row per block; PLAIN stores (nt-store hypothesis test) ----------------
// Round-0/1/2 all ran ~41.8 us regardless of q/k path or occupancy; the one invariant
// was the nontemporal C-store. Plain full-line dwordx4 stores drain at 6.6 TB/s (fill proof).
__global__ __launch_bounds__(256) void k2_rowC(
    const float* __restrict__ cp, const float* __restrict__ n_prev,
    float* __restrict__ ws, float* __restrict__ C_out, float* __restrict__ n_out)
{
    const int lane = threadIdx.x & 63;
    const int wid  = threadIdx.x >> 6;

    if (blockIdx.x == MM) {
        __shared__ float pred[4];
        const float it = ws[3 * MM + 0];
        const float ft = ws[3 * MM + 1];
        const float4* np4 = (const float4*)n_prev;
        const float4* kv4 = (const float4*)(ws + MM);
        const float4* qv4 = (const float4*)ws;
        float4* n4 = (float4*)n_out;
        float acc = 0.f;
        #pragma unroll
        for (int u = 0; u < 4; ++u) {
            int t = threadIdx.x + 256 * u;
            float4 np = np4[t], kk = kv4[t], qq = qv4[t];
            float4 nn;
            nn.x = fmaf(ft, np.x, it * kk.x);
            nn.y = fmaf(ft, np.y, it * kk.y);
            nn.z = fmaf(ft, np.z, it * kk.z);
            nn.w = fmaf(ft, np.w, it * kk.w);
            n4[t] = nn;
            acc += nn.x * qq.x + nn.y * qq.y + nn.z * qq.z + nn.w * qq.w;
        }
        for (int off = 32; off; off >>= 1) acc += __shfl_down(acc, off, 64);
        if (lane == 0) pred[wid] = acc;
        __syncthreads();
        if (threadIdx.x == 0) {
            float s = pred[0] + pred[1] + pred[2] + pred[3];
            ws[3 * MM + 3] = fmaxf(fabsf(s), 1.0f);
        }
        return;
    }

    __shared__ float sred[4];
    const int row = blockIdx.x;
    const float it  = ws[3 * MM + 0];
    const float ft  = ws[3 * MM + 1];
    const float ivi = it * ws[2 * MM + row];

    const float4* cprow = (const float4*)(cp + (size_t)row * MM);
    const float4* kv4   = (const float4*)(ws + MM);
    const float4* qv4   = (const float4*)ws;
    float4*       crow  = (float4*)(C_out + (size_t)row * MM);

    float4 c[4], kk[4], qq[4];
    #pragma unroll
    for (int u = 0; u < 4; ++u) c[u]  = cprow[threadIdx.x + 256 * u];
    #pragma unroll
    for (int u = 0; u < 4; ++u) kk[u] = kv4[threadIdx.x + 256 * u];
    #pragma unroll
    for (int u = 0; u < 4; ++u) qq[u] = qv4[threadIdx.x + 256 * u];

    float acc = 0.f;
    #pragma unroll
    for (int u = 0; u < 4; ++u) {
        float4 o;
        o.x = fmaf(ivi, kk[u].x, ft * c[u].x);
        o.y = fmaf(ivi, kk[u].y, ft * c[u].y);
        o.z = fmaf(ivi, kk[u].z, ft * c[u].z);
        o.w = fmaf(ivi, kk[u].w, ft * c[u].w);
        crow[threadIdx.x + 256 * u] = o;          // plain store (was nontemporal)
        acc += o.x * qq[u].x + o.y * qq[u].y + o.z * qq[u].z + o.w * qq[u].w;
    }
    for (int off = 32; off; off >>= 1) acc += __shfl_down(acc, off, 64);
    if (lane == 0) sred[wid] = acc;
    __syncthreads();
    if (threadIdx.x == 0)
        ws[4 * MM + row] = sred[0] + sred[1] + sred[2] + sred[3];
}

// ---------------- K3: ht = ot * num / denom ----------------
__global__ __launch_bounds__(256) void k3_finalize(
    const float* __restrict__ ws, float* __restrict__ ht_out)
{
    const float ot    = ws[3 * MM + 2];
    const float denom = ws[3 * MM + 3];
    const int i = blockIdx.x * 256 + threadIdx.x;
    ht_out[i] = ot * (ws[4 * MM + i] / denom);
}

extern "C" void kernel_launch(void* const* d_in, const int* in_sizes, int n_in,
                              void* d_out, int out_size, void* d_ws, size_t ws_size,
                              hipStream_t stream)
{
    const float* x      = (const float*)d_in[0];
    const float* cp     = (const float*)d_in[1];
    const float* n_prev = (const float*)d_in[2];
    const float* Wq = (const float*)d_in[3];
    const float* bq = (const float*)d_in[4];
    const float* Wk = (const float*)d_in[5];
    const float* bk = (const float*)d_in[6];
    const float* Wv = (const float*)d_in[7];
    const float* bV = (const float*)d_in[8];
    const float* Wi = (const float*)d_in[9];
    const float* bi = (const float*)d_in[10];
    const float* Wf = (const float*)d_in[11];
    const float* bf = (const float*)d_in[12];
    const float* Wo = (const float*)d_in[13];
    const float* bo = (const float*)d_in[14];

    float* out = (float*)d_out;
    float* ht  = out;                        // (M,1)
    float* C   = out + MM;                   // (M,M)
    float* n   = out + MM + (size_t)MM * MM; // (M,1)
    float* ws  = (float*)d_ws;

    k1_gemv_gates<<<3075, 256, 0, stream>>>(x, Wq, bq, Wk, bk, Wv, bV,
                                            Wi, bi, Wf, bf, Wo, bo, ws);
    k2_rowC      <<<MM + 1, 256, 0, stream>>>(cp, n_prev, ws, C, n);
    k3_finalize  <<<MM / 256, 256, 0, stream>>>(ws, ht);
}